// Round 18
// baseline (205.605 us; speedup 1.0000x reference)
//
#include <hip/hip_runtime.h>

// ---------------------------------------------------------------------------
// CausalSelfAttention fused block, MI355X (gfx950)
// Round 17: r15's verified flash body, with the qtile-pair mapping replaced
// by a constant-CU-sum bijection under the stride-256 round-robin block->CU
// deal (established r14): p = j>>1, L = p&15, k = p>>4,
//   jj = {2L, 63-2L, 2L+1, 62-2L}[k]
// -> every CU's 4 dealt blocks sum to exactly 130 window-units (was 100-160),
// and all 4 share the same head (K/V L2 reuse). Everything else unchanged.
// ---------------------------------------------------------------------------

typedef __attribute__((ext_vector_type(8)))  short  short8;
typedef __attribute__((ext_vector_type(4)))  float  f32x4;
typedef __attribute__((ext_vector_type(16))) float  f32x16;
typedef __attribute__((ext_vector_type(4)))  float  float4v;
typedef __attribute__((ext_vector_type(4)))  unsigned short ushort4v;
typedef __attribute__((ext_vector_type(4)))  unsigned int   uint4v;

#define S_LEN 4096
#define DMODEL 1024
#define NHEADS 16
#define DKH 64

// 0.125 * log2(e): folds 1/sqrt(64) and the exp->exp2 conversion into Q.
#define QSCALE 0.18033688011112042f

__device__ __forceinline__ unsigned short f2bf(float f) {
  unsigned u = __builtin_bit_cast(unsigned, f);
  u += 0x7FFFu + ((u >> 16) & 1u);   // round-to-nearest-even
  return (unsigned short)(u >> 16);
}
__device__ __forceinline__ float bf2f(unsigned short h) {
  return __builtin_bit_cast(float, ((unsigned)h) << 16);
}

// async global->LDS, 16B per lane (linear dest: uniform base + lane*16).
#define GLDS16(gsrc, ldst)                                                   \
  __builtin_amdgcn_global_load_lds(                                          \
      (const __attribute__((address_space(1))) void*)(gsrc),                 \
      (__attribute__((address_space(3))) void*)(ldst), 16, 0, 0)

// ---------------------------------------------------------------------------
// fp32 -> bf16 conversion for all three inputs + RoPE cos/sin table.
// ---------------------------------------------------------------------------
#define CVT_TOTAL (1048576 + 786432 + 262144)
__global__ void cvt_bf16_all(const float* __restrict__ x,    unsigned short* __restrict__ xb,
                             const float* __restrict__ wq,   unsigned short* __restrict__ wqb,
                             const float* __restrict__ wo,   unsigned short* __restrict__ wob,
                             float2* __restrict__ tab) {
  int i = blockIdx.x * blockDim.x + threadIdx.x;
  if (i < CVT_TOTAL) {
    const float* src; unsigned short* dst; int off;
    if (i < 1048576)               { src = x;  dst = xb;  off = i; }
    else if (i < 1048576 + 786432) { src = wq; dst = wqb; off = i - 1048576; }
    else                           { src = wo; dst = wob; off = i - 1048576 - 786432; }
    float4v v = reinterpret_cast<const float4v*>(src)[off];
    ushort4v o;
    o[0] = f2bf(v[0]); o[1] = f2bf(v[1]); o[2] = f2bf(v[2]); o[3] = f2bf(v[3]);
    reinterpret_cast<ushort4v*>(dst)[off] = o;
  } else {
    int id = i - CVT_TOTAL;                      // 0 .. 131071
    if (id < S_LEN * 32) {
      int s = id >> 5, fi = id & 31;
      float inv = expf(-(float)(2 * fi) * (9.2103403719761836f / 64.0f));
      float ang = (float)s * inv;
      float sn, cs;
      sincosf(ang, &sn, &cs);
      tab[id] = make_float2(cs, sn);
    }
  }
}

// ---------------------------------------------------------------------------
// GEMM1 + fused RoPE epilogue.  qkv = x . Wqkv^T  (M=4096, N=3072, K=1024).
// Q -> rope*QSCALE -> Qr[h][s][64];  K -> rope -> Kr[h][s][64];
// V -> written DIRECTLY transposed to Vt[h][64][S] (4 consecutive s / store).
// ---------------------------------------------------------------------------
__global__ __launch_bounds__(256) void gemm_qkv(const unsigned short* __restrict__ A,
                                                const unsigned short* __restrict__ B,
                                                const float2* __restrict__ tab,
                                                unsigned short* __restrict__ Qr,
                                                unsigned short* __restrict__ Kr,
                                                unsigned short* __restrict__ Vt) {
  const int K = 1024;
  __shared__ __align__(16) unsigned short As[128 * 32];
  __shared__ __align__(16) unsigned short Bs[128 * 32];

  const int tid = threadIdx.x;
  const int l = tid & 63, w = tid >> 6;
  const int wr = w >> 1, wc = w & 1;
  const int bm = blockIdx.y * 128, bn = blockIdx.x * 128;
  const int lr = l & 15, lk = (l >> 4) * 8;

  f32x4 acc[4][4] = {};

  const unsigned short* Ag0 = A + (size_t)(bm + (tid >> 2)) * K + (tid & 3) * 8;
  const unsigned short* Ag1 = A + (size_t)(bm + 64 + (tid >> 2)) * K + (tid & 3) * 8;
  const unsigned short* Bg0 = B + (size_t)(bn + (tid >> 2)) * K + (tid & 3) * 8;
  const unsigned short* Bg1 = B + (size_t)(bn + 64 + (tid >> 2)) * K + (tid & 3) * 8;
  unsigned short* Ad0 = As + tid * 8;
  unsigned short* Ad1 = As + (tid + 256) * 8;
  unsigned short* Bd0 = Bs + tid * 8;
  unsigned short* Bd1 = Bs + (tid + 256) * 8;

  const unsigned short* Afr = As + (wr * 64 + lr) * 32 + lk;
  const unsigned short* Bfr = Bs + (wc * 64 + lr) * 32 + lk;

  for (int k0 = 0; k0 < K; k0 += 32) {
    GLDS16(Ag0 + k0, Ad0);
    GLDS16(Ag1 + k0, Ad1);
    GLDS16(Bg0 + k0, Bd0);
    GLDS16(Bg1 + k0, Bd1);
    __syncthreads();

    short8 af[4], bfr[4];
#pragma unroll
    for (int mi = 0; mi < 4; mi++) af[mi]  = *(const short8*)(Afr + mi * 16 * 32);
#pragma unroll
    for (int ni = 0; ni < 4; ni++) bfr[ni] = *(const short8*)(Bfr + ni * 16 * 32);

#pragma unroll
    for (int mi = 0; mi < 4; mi++)
#pragma unroll
      for (int ni = 0; ni < 4; ni++)
        acc[mi][ni] = __builtin_amdgcn_mfma_f32_16x16x32_bf16(af[mi], bfr[ni],
                                                              acc[mi][ni], 0, 0, 0);
    __syncthreads();
  }

  const int row0 = bm + wr * 64 + (l >> 4) * 4;
  const int region = bn >> 10;                    // 0 Q, 1 K, 2 V (uniform)
  if (region < 2) {
    const int base64 = (bn & 1023) + wc * 64;
    const int h = base64 >> 6;
    unsigned short* dst = region ? Kr : Qr;
    const float scale = region ? 1.0f : QSCALE;
    const size_t hb = (size_t)h * S_LEN * DKH;
#pragma unroll
    for (int mi = 0; mi < 4; mi++)
#pragma unroll
      for (int jj = 0; jj < 4; jj++) {
        const int s = row0 + mi * 16 + jj;
        const float2 cs0 = tab[s * 32 + lr];
        const float2 cs1 = tab[s * 32 + lr + 16];
        const float x1 = acc[mi][0][jj], x2 = acc[mi][2][jj];
        const float y1 = acc[mi][1][jj], y2 = acc[mi][3][jj];
        const float o0 = (x1 * cs0.x - x2 * cs0.y) * scale;
        const float o2 = (x2 * cs0.x + x1 * cs0.y) * scale;
        const float o1 = (y1 * cs1.x - y2 * cs1.y) * scale;
        const float o3 = (y2 * cs1.x + y1 * cs1.y) * scale;
        const size_t a = hb + (size_t)s * DKH + lr;
        dst[a]      = f2bf(o0);
        dst[a + 16] = f2bf(o1);
        dst[a + 32] = f2bf(o2);
        dst[a + 48] = f2bf(o3);
      }
  } else {
    // V: acc[mi][ni][0..3] are 4 consecutive s at fixed d -> short4 store
    const int colh = (bn - 2048) + wc * 64;       // multiple of 64
    const int h = colh >> 6;
    unsigned short* base = Vt + (size_t)h * DKH * S_LEN;
#pragma unroll
    for (int mi = 0; mi < 4; mi++) {
      const int s = row0 + mi * 16;
#pragma unroll
      for (int ni = 0; ni < 4; ni++) {
        const int d = ni * 16 + lr;
        ushort4v pk;
        pk[0] = f2bf(acc[mi][ni][0]);
        pk[1] = f2bf(acc[mi][ni][1]);
        pk[2] = f2bf(acc[mi][ni][2]);
        pk[3] = f2bf(acc[mi][ni][3]);
        *(ushort4v*)(base + (size_t)d * S_LEN + s) = pk;
      }
    }
  }
}

// ---------------------------------------------------------------------------
// m97-structure GEMM (f32 out): out = O . Wo^T.
// ---------------------------------------------------------------------------
__global__ __launch_bounds__(256) void gemm_lds_f32(const unsigned short* __restrict__ A,
                                                    const unsigned short* __restrict__ B,
                                                    float* __restrict__ Cp,
                                                    int M, int N, int K) {
  __shared__ __align__(16) unsigned short As[128 * 32];
  __shared__ __align__(16) unsigned short Bs[128 * 32];

  const int tid = threadIdx.x;
  const int l = tid & 63, w = tid >> 6;
  const int wr = w >> 1, wc = w & 1;
  const int bm = blockIdx.y * 128, bn = blockIdx.x * 128;
  const int lr = l & 15, lk = (l >> 4) * 8;

  f32x4 acc[4][4] = {};

  const unsigned short* Ag0 = A + (size_t)(bm + (tid >> 2)) * K + (tid & 3) * 8;
  const unsigned short* Ag1 = A + (size_t)(bm + 64 + (tid >> 2)) * K + (tid & 3) * 8;
  const unsigned short* Bg0 = B + (size_t)(bn + (tid >> 2)) * K + (tid & 3) * 8;
  const unsigned short* Bg1 = B + (size_t)(bn + 64 + (tid >> 2)) * K + (tid & 3) * 8;
  unsigned short* Ad0 = As + tid * 8;
  unsigned short* Ad1 = As + (tid + 256) * 8;
  unsigned short* Bd0 = Bs + tid * 8;
  unsigned short* Bd1 = Bs + (tid + 256) * 8;

  const unsigned short* Afr = As + (wr * 64 + lr) * 32 + lk;
  const unsigned short* Bfr = Bs + (wc * 64 + lr) * 32 + lk;

  for (int k0 = 0; k0 < K; k0 += 32) {
    GLDS16(Ag0 + k0, Ad0);
    GLDS16(Ag1 + k0, Ad1);
    GLDS16(Bg0 + k0, Bd0);
    GLDS16(Bg1 + k0, Bd1);
    __syncthreads();

    short8 af[4], bfr[4];
#pragma unroll
    for (int mi = 0; mi < 4; mi++) af[mi]  = *(const short8*)(Afr + mi * 16 * 32);
#pragma unroll
    for (int ni = 0; ni < 4; ni++) bfr[ni] = *(const short8*)(Bfr + ni * 16 * 32);

#pragma unroll
    for (int mi = 0; mi < 4; mi++)
#pragma unroll
      for (int ni = 0; ni < 4; ni++)
        acc[mi][ni] = __builtin_amdgcn_mfma_f32_16x16x32_bf16(af[mi], bfr[ni],
                                                              acc[mi][ni], 0, 0, 0);
    __syncthreads();
  }

  const int row0 = bm + wr * 64 + (l >> 4) * 4;
  const int col0 = bn + wc * 64 + lr;
#pragma unroll
  for (int mi = 0; mi < 4; mi++)
#pragma unroll
    for (int ni = 0; ni < 4; ni++)
#pragma unroll
      for (int j = 0; j < 4; j++)
        Cp[(size_t)(row0 + mi * 16 + j) * N + (col0 + ni * 16)] = acc[mi][ni][j];
}

// ---------------------------------------------------------------------------
// Flash attention: round-12/15 verified body. 2 adjacent q-subtiles (64
// q-rows) per block, 64-key double-buffered windows, one barrier per window.
// Wave w: q-subtile w>>1, chunk parity w&1. qtile-pair mapping: constant
// per-CU-sum bijection (see header comment).
// ---------------------------------------------------------------------------
__global__ __launch_bounds__(256) void flash_attn_kernel(const unsigned short* __restrict__ Qr,
                                                         const unsigned short* __restrict__ Kr,
                                                         const unsigned short* __restrict__ Vt,
                                                         unsigned short* __restrict__ O) {
  // per buffer: [0,8K) K (64 keys x 128B), [8K,16K) V (64 d x 128B)
  __shared__ __align__(16) char smem[2][16384];

  const int tid = threadIdx.x;
  const int l  = tid & 63;
  const int w  = tid >> 6;            // wave 0..3
  const int r  = l & 31;
  const int hi = l >> 5;
  const int wsub = w >> 1;            // q-subtile 0/1
  const int wpar = w & 1;             // chunk parity

  // XCD-pinned head mapping + constant-CU-sum q-pair bijection.
  // Deal model (r14 evidence): CU i gets bx in {i, i+256, i+512, i+768}
  // -> p in {P, P+16, P+32, P+48}. jj = {2L, 63-2L, 2L+1, 62-2L}[p>>4]
  // (L = p&15) gives per-CU window-sum = 130 for every CU.
  const int bx  = blockIdx.x;            // 0..1023
  const int xcd = bx & 7;
  const int j   = bx >> 3;               // 0..127
  const int h   = xcd * 2 + (j & 1);     // 2 heads per XCD
  const int p   = j >> 1;                // 0..63
  const int L   = p & 15, k4 = p >> 4;
  const int jj  = (k4 == 0) ? (2 * L)
                : (k4 == 1) ? (63 - 2 * L)
                : (k4 == 2) ? (2 * L + 1)
                            : (62 - 2 * L);
  const int q0  = jj * 64;

  const unsigned short* Qh = Qr + (size_t)h * S_LEN * DKH;
  const unsigned short* Kh = Kr + (size_t)h * S_LEN * DKH;
  const unsigned short* Vh = Vt + (size_t)h * DKH * S_LEN;

  const int qtile_w = 2 * jj + wsub;     // this wave's chunk-index ceiling
  const int qbase   = q0 + wsub * 32;

  // --- staging constants: K rows = keys (64 x 128B), V rows = d (64 x 128B)
  const int srow = tid >> 3;                                     // 0..31
  const int scol = (((tid & 7) * 16) ^ ((srow & 7) << 4)) >> 1;  // elem in row
  const size_t kbase = (size_t)srow * DKH + scol;    // Kh[key][d]
  const size_t vbase = (size_t)srow * S_LEN + scol;  // Vh[d][key]

  // --- fragment-read constants ---
  const int sw      = (r & 7) << 4;                // XOR swizzle for reads
  const int kfbyte  = (wpar * 32 + r) * 128;       // K row base (bytes)
  const int vfbyte0 = r * 128;                     // V rows r / r+32 (bytes)
  const int vfbyte1 = (r + 32) * 128;
  const int vcol    = wpar * 64 + hi * 16;         // V key-col base (bytes)

  // Q B-fragments for this wave's q-subtile
  short8 qf[4];
  {
    const unsigned short* qb = Qh + (size_t)(qbase + r) * 64 + hi * 8;
#pragma unroll
    for (int dc = 0; dc < 4; dc++) qf[dc] = *(const short8*)(qb + dc * 16);
  }

  f32x16 acc0 = {}, acc1 = {};     // O^T tiles: d 0..31 / 32..63, col=q
  float m = -1e30f, lsum = 0.0f;

  const int nwin = jj + 1;         // 64-key windows

  // --- prologue: stage window 0 into buf 0 ---
#pragma unroll
  for (int i = 0; i < 2; i++) {
    GLDS16(Kh + kbase + (size_t)i * 32 * DKH,   smem[0] + i * 4096 + tid * 16);
    GLDS16(Vh + vbase + (size_t)i * 32 * S_LEN, smem[0] + 8192 + i * 4096 + tid * 16);
  }
  __syncthreads();

  int buf = 0;
  for (int it = 0; it < nwin; it++) {
    // issue next window's staging into the other buffer (lands under compute)
    if (it + 1 < nwin) {
      char* sd = smem[buf ^ 1];
      const unsigned short* Kg = Kh + (size_t)(it + 1) * 64 * DKH;
      const unsigned short* Vg = Vh + (size_t)(it + 1) * 64;
#pragma unroll
      for (int i = 0; i < 2; i++) {
        GLDS16(Kg + kbase + (size_t)i * 32 * DKH,   sd + i * 4096 + tid * 16);
        GLDS16(Vg + vbase + (size_t)i * 32 * S_LEN, sd + 8192 + i * 4096 + tid * 16);
      }
    }

    const char* sm = smem[buf];
    const int c = 2 * it + wpar;
    if (c <= qtile_w) {
      // --- fragments from LDS (swizzled reads) ---
      short8 kf[4], vf[4];
#pragma unroll
      for (int dc = 0; dc < 4; dc++)
        kf[dc] = *(const short8*)(sm + kfbyte + ((dc * 32 + hi * 16) ^ sw));
#pragma unroll
      for (int kc = 0; kc < 2; kc++) {
        vf[kc]     = *(const short8*)(sm + 8192 + vfbyte0 + ((vcol + kc * 32) ^ sw));
        vf[2 + kc] = *(const short8*)(sm + 8192 + vfbyte1 + ((vcol + kc * 32) ^ sw));
      }

      // --- S^T = K . Q^T ---
      f32x16 st = {};
      __builtin_amdgcn_s_setprio(1);
      st = __builtin_amdgcn_mfma_f32_32x32x16_bf16(kf[0], qf[0], st, 0, 0, 0);
      st = __builtin_amdgcn_mfma_f32_32x32x16_bf16(kf[1], qf[1], st, 0, 0, 0);
      st = __builtin_amdgcn_mfma_f32_32x32x16_bf16(kf[2], qf[2], st, 0, 0, 0);
      st = __builtin_amdgcn_mfma_f32_32x32x16_bf16(kf[3], qf[3], st, 0, 0, 0);
      __builtin_amdgcn_s_setprio(0);

      // causal mask: only the diagonal chunk
      if (c == qtile_w) {
#pragma unroll
        for (int reg = 0; reg < 16; reg++) {
          const int koff = (reg & 3) + 8 * (reg >> 2) + 4 * hi;
          if (koff > r) st[reg] = -1e30f;
        }
      }

      // --- lane-local online softmax (exp2 domain) ---
      float t0 = fmaxf(fmaxf(st[0],  st[1]),  st[2]);
      float t1 = fmaxf(fmaxf(st[3],  st[4]),  st[5]);
      float t2 = fmaxf(fmaxf(st[6],  st[7]),  st[8]);
      float t3 = fmaxf(fmaxf(st[9],  st[10]), st[11]);
      float t4 = fmaxf(fmaxf(st[12], st[13]), st[14]);
      float pm = fmaxf(fmaxf(fmaxf(t0, t1), fmaxf(t2, t3)), fmaxf(t4, st[15]));
      pm = fmaxf(pm, __shfl_xor(pm, 32));

      if (!__all(pm <= m + 8.0f)) {     // defer-max (T13, THR=8)
        float mn  = fmaxf(m, pm);
        float scl = exp2f(m - mn);
        m = mn;
        lsum *= scl;
#pragma unroll
        for (int reg = 0; reg < 16; reg++) { acc0[reg] *= scl; acc1[reg] *= scl; }
      }

      float p2[16];
#pragma unroll
      for (int reg = 0; reg < 16; reg++) p2[reg] = exp2f(st[reg] - m);

      float s2[8];
#pragma unroll
      for (int i = 0; i < 8; i++) s2[i] = p2[2 * i] + p2[2 * i + 1];
#pragma unroll
      for (int i = 0; i < 4; i++) s2[i] = s2[i] + s2[i + 4];
      float rs = (s2[0] + s2[2]) + (s2[1] + s2[3]);
      rs += __shfl_xor(rs, 32);
      lsum += rs;

      // --- pack P to bf16 B-fragments (verified shfl_xor exchange) ---
      unsigned wd[8];
#pragma unroll
      for (int i = 0; i < 8; i++) {
        asm("v_cvt_pk_bf16_f32 %0, %1, %2" : "=v"(wd[i]) : "v"(p2[2 * i]), "v"(p2[2 * i + 1]));
      }
      unsigned pw[8];
#pragma unroll
      for (int i = 0; i < 8; i++) pw[i] = __shfl_xor(wd[i], 32);

      uint4v u0, u1;
      u0[0] = hi ? pw[2] : wd[0];
      u0[1] = hi ? pw[3] : wd[1];
      u0[2] = hi ? wd[2] : pw[0];
      u0[3] = hi ? wd[3] : pw[1];
      u1[0] = hi ? pw[6] : wd[4];
      u1[1] = hi ? pw[7] : wd[5];
      u1[2] = hi ? wd[6] : pw[4];
      u1[3] = hi ? wd[7] : pw[5];
      short8 pa0 = __builtin_bit_cast(short8, u0);
      short8 pa1 = __builtin_bit_cast(short8, u1);

      // --- O^T += V^T . P ---
      __builtin_amdgcn_s_setprio(1);
      acc0 = __builtin_amdgcn_mfma_f32_32x32x16_bf16(vf[0], pa0, acc0, 0, 0, 0);
      acc0 = __builtin_amdgcn_mfma_f32_32x32x16_bf16(vf[1], pa1, acc0, 0, 0, 0);
      acc1 = __builtin_amdgcn_mfma_f32_32x32x16_bf16(vf[2], pa0, acc1, 0, 0, 0);
      acc1 = __builtin_amdgcn_mfma_f32_32x32x16_bf16(vf[3], pa1, acc1, 0, 0, 0);
      __builtin_amdgcn_s_setprio(0);
    }

    __syncthreads();   // buf reads done + buf^1 staging complete
    buf ^= 1;
  }

  // --- LSE combine: 2 partials per q-subtile (buffers alias smem) ---
  unsigned (*oaccp)[32][33] = (unsigned (*)[32][33])smem;   // 16.9 KB
  float* mlm = (float*)((char*)smem + 16896);               // 128 floats
  float* mll = (float*)((char*)smem + 17408);               // 128 floats

  if (hi == 0) { mlm[w * 32 + r] = m; mll[w * 32 + r] = lsum; }
#pragma unroll
  for (int i = 0; i < 8; i++) {
    const int widx = 4 * (i >> 1) + 2 * hi + (i & 1);
    unsigned ua, ub;
    asm("v_cvt_pk_bf16_f32 %0, %1, %2" : "=v"(ua) : "v"(acc0[2 * i]), "v"(acc0[2 * i + 1]));
    asm("v_cvt_pk_bf16_f32 %0, %1, %2" : "=v"(ub) : "v"(acc1[2 * i]), "v"(acc1[2 * i + 1]));
    oaccp[w][r][widx]      = ua;
    oaccp[w][r][16 + widx] = ub;
  }
  __syncthreads();

  // thread -> (subtile st, q, word-group of 8)
  const int st  = tid >> 7;            // 0/1
  const int rem = tid & 127;
  const int q   = rem >> 2;            // 0..31
  const int c0  = (rem & 3) * 8;       // word index 0,8,16,24
  const int w0  = 2 * st, w1 = 2 * st + 1;

  const float m0 = mlm[w0 * 32 + q], m1 = mlm[w1 * 32 + q];
  const float mmax = fmaxf(m0, m1);
  const float sc0 = exp2f(m0 - mmax), sc1 = exp2f(m1 - mmax);
  const float ltot = sc0 * mll[w0 * 32 + q] + sc1 * mll[w1 * 32 + q];
  const float rinv = 1.0f / ltot;

  float vs[16];
#pragma unroll
  for (int i = 0; i < 8; i++) {
    unsigned ua = oaccp[w0][q][c0 + i];
    unsigned ub = oaccp[w1][q][c0 + i];
    vs[2 * i]     = sc0 * __builtin_bit_cast(float, ua << 16)
                  + sc1 * __builtin_bit_cast(float, ub << 16);
    vs[2 * i + 1] = sc0 * __builtin_bit_cast(float, ua & 0xFFFF0000u)
                  + sc1 * __builtin_bit_cast(float, ub & 0xFFFF0000u);
  }
  short8 ov0, ov1;
#pragma unroll
  for (int i = 0; i < 8; i++) {
    ov0[i] = (short)f2bf(vs[i] * rinv);
    ov1[i] = (short)f2bf(vs[8 + i] * rinv);
  }
  unsigned short* op = O + (size_t)(q0 + st * 32 + q) * DMODEL + h * 64 + c0 * 2;
  *(short8*)(op)     = ov0;
  *(short8*)(op + 8) = ov1;
}

// ---------------------------------------------------------------------------
// launch
// ---------------------------------------------------------------------------
extern "C" void kernel_launch(void* const* d_in, const int* in_sizes, int n_in,
                              void* d_out, int out_size, void* d_ws, size_t ws_size,
                              hipStream_t stream) {
  (void)in_sizes; (void)n_in; (void)out_size; (void)ws_size;
  const float* x    = (const float*)d_in[0];   // [4096,1024]
  const float* Wqkv = (const float*)d_in[1];   // [3072,1024]
  const float* Wo   = (const float*)d_in[2];   // [1024,1024]
  float* out = (float*)d_out;                  // [4096,1024]

  char* ws = (char*)d_ws;
  const size_t MB = 1u << 20;
  unsigned short* x_bf    = (unsigned short*)(ws + 0 * MB);
  unsigned short* wqkv_bf = (unsigned short*)(ws + 8 * MB);
  unsigned short* wo_bf   = (unsigned short*)(ws + 14 * MB);
  float2*         tab     = (float2*)(ws + 24 * MB);           //  1 MB
  unsigned short* Qr      = (unsigned short*)(ws + 40 * MB);
  unsigned short* Kr      = (unsigned short*)(ws + 48 * MB);
  unsigned short* Vt      = (unsigned short*)(ws + 56 * MB);
  unsigned short* Obf     = (unsigned short*)(ws + 64 * MB);

  // cvt (2,097,152 float4s) + rope table (131,072 entries) in one launch
  cvt_bf16_all<<<(CVT_TOTAL + 131072 + 255) / 256, 256, 0, stream>>>(
      x, x_bf, Wqkv, wqkv_bf, Wo, wo_bf, tab);

  // qkv = x . Wqkv^T with fused RoPE epilogue; V written transposed to Vt
  gemm_qkv<<<dim3(3072 / 128, 4096 / 128), 256, 0, stream>>>(x_bf, wqkv_bf, tab,
                                                             Qr, Kr, Vt);

  flash_attn_kernel<<<1024, 256, 0, stream>>>(Qr, Kr, Vt, Obf);

  // out = O . Wo^T : M=4096, N=1024, K=1024
  gemm_lds_f32<<<dim3(1024 / 128, 4096 / 128), 256, 0, stream>>>(Obf, wo_bf, out,
                                                                 4096, 1024, 1024);
}

// Round 19
// 171.684 us; speedup vs baseline: 1.1976x; 1.1976x over previous
//
#include <hip/hip_runtime.h>

// ---------------------------------------------------------------------------
// CausalSelfAttention fused block, MI355X (gfx950)
// Round 18: restore the verified round-15 configuration exactly (172.0 us).
// Flash: r12 body, monotone longest-first mapping (LPT-greedy under dynamic
// dispatch — r14/r16/r17 mapping/balance experiments all regressed).
// gemm_qkv: fused RoPE epilogue + direct-transposed V. cvt+rope-table fused.
// ---------------------------------------------------------------------------

typedef __attribute__((ext_vector_type(8)))  short  short8;
typedef __attribute__((ext_vector_type(4)))  float  f32x4;
typedef __attribute__((ext_vector_type(16))) float  f32x16;
typedef __attribute__((ext_vector_type(4)))  float  float4v;
typedef __attribute__((ext_vector_type(4)))  unsigned short ushort4v;
typedef __attribute__((ext_vector_type(4)))  unsigned int   uint4v;

#define S_LEN 4096
#define DMODEL 1024
#define NHEADS 16
#define DKH 64

// 0.125 * log2(e): folds 1/sqrt(64) and the exp->exp2 conversion into Q.
#define QSCALE 0.18033688011112042f

__device__ __forceinline__ unsigned short f2bf(float f) {
  unsigned u = __builtin_bit_cast(unsigned, f);
  u += 0x7FFFu + ((u >> 16) & 1u);   // round-to-nearest-even
  return (unsigned short)(u >> 16);
}
__device__ __forceinline__ float bf2f(unsigned short h) {
  return __builtin_bit_cast(float, ((unsigned)h) << 16);
}

// async global->LDS, 16B per lane (linear dest: uniform base + lane*16).
#define GLDS16(gsrc, ldst)                                                   \
  __builtin_amdgcn_global_load_lds(                                          \
      (const __attribute__((address_space(1))) void*)(gsrc),                 \
      (__attribute__((address_space(3))) void*)(ldst), 16, 0, 0)

// ---------------------------------------------------------------------------
// fp32 -> bf16 conversion for all three inputs + RoPE cos/sin table.
// ---------------------------------------------------------------------------
#define CVT_TOTAL (1048576 + 786432 + 262144)
__global__ void cvt_bf16_all(const float* __restrict__ x,    unsigned short* __restrict__ xb,
                             const float* __restrict__ wq,   unsigned short* __restrict__ wqb,
                             const float* __restrict__ wo,   unsigned short* __restrict__ wob,
                             float2* __restrict__ tab) {
  int i = blockIdx.x * blockDim.x + threadIdx.x;
  if (i < CVT_TOTAL) {
    const float* src; unsigned short* dst; int off;
    if (i < 1048576)               { src = x;  dst = xb;  off = i; }
    else if (i < 1048576 + 786432) { src = wq; dst = wqb; off = i - 1048576; }
    else                           { src = wo; dst = wob; off = i - 1048576 - 786432; }
    float4v v = reinterpret_cast<const float4v*>(src)[off];
    ushort4v o;
    o[0] = f2bf(v[0]); o[1] = f2bf(v[1]); o[2] = f2bf(v[2]); o[3] = f2bf(v[3]);
    reinterpret_cast<ushort4v*>(dst)[off] = o;
  } else {
    int id = i - CVT_TOTAL;                      // 0 .. 131071
    if (id < S_LEN * 32) {
      int s = id >> 5, fi = id & 31;
      float inv = expf(-(float)(2 * fi) * (9.2103403719761836f / 64.0f));
      float ang = (float)s * inv;
      float sn, cs;
      sincosf(ang, &sn, &cs);
      tab[id] = make_float2(cs, sn);
    }
  }
}

// ---------------------------------------------------------------------------
// GEMM1 + fused RoPE epilogue.  qkv = x . Wqkv^T  (M=4096, N=3072, K=1024).
// Q -> rope*QSCALE -> Qr[h][s][64];  K -> rope -> Kr[h][s][64];
// V -> written DIRECTLY transposed to Vt[h][64][S] (4 consecutive s / store).
// ---------------------------------------------------------------------------
__global__ __launch_bounds__(256) void gemm_qkv(const unsigned short* __restrict__ A,
                                                const unsigned short* __restrict__ B,
                                                const float2* __restrict__ tab,
                                                unsigned short* __restrict__ Qr,
                                                unsigned short* __restrict__ Kr,
                                                unsigned short* __restrict__ Vt) {
  const int K = 1024;
  __shared__ __align__(16) unsigned short As[128 * 32];
  __shared__ __align__(16) unsigned short Bs[128 * 32];

  const int tid = threadIdx.x;
  const int l = tid & 63, w = tid >> 6;
  const int wr = w >> 1, wc = w & 1;
  const int bm = blockIdx.y * 128, bn = blockIdx.x * 128;
  const int lr = l & 15, lk = (l >> 4) * 8;

  f32x4 acc[4][4] = {};

  const unsigned short* Ag0 = A + (size_t)(bm + (tid >> 2)) * K + (tid & 3) * 8;
  const unsigned short* Ag1 = A + (size_t)(bm + 64 + (tid >> 2)) * K + (tid & 3) * 8;
  const unsigned short* Bg0 = B + (size_t)(bn + (tid >> 2)) * K + (tid & 3) * 8;
  const unsigned short* Bg1 = B + (size_t)(bn + 64 + (tid >> 2)) * K + (tid & 3) * 8;
  unsigned short* Ad0 = As + tid * 8;
  unsigned short* Ad1 = As + (tid + 256) * 8;
  unsigned short* Bd0 = Bs + tid * 8;
  unsigned short* Bd1 = Bs + (tid + 256) * 8;

  const unsigned short* Afr = As + (wr * 64 + lr) * 32 + lk;
  const unsigned short* Bfr = Bs + (wc * 64 + lr) * 32 + lk;

  for (int k0 = 0; k0 < K; k0 += 32) {
    GLDS16(Ag0 + k0, Ad0);
    GLDS16(Ag1 + k0, Ad1);
    GLDS16(Bg0 + k0, Bd0);
    GLDS16(Bg1 + k0, Bd1);
    __syncthreads();

    short8 af[4], bfr[4];
#pragma unroll
    for (int mi = 0; mi < 4; mi++) af[mi]  = *(const short8*)(Afr + mi * 16 * 32);
#pragma unroll
    for (int ni = 0; ni < 4; ni++) bfr[ni] = *(const short8*)(Bfr + ni * 16 * 32);

#pragma unroll
    for (int mi = 0; mi < 4; mi++)
#pragma unroll
      for (int ni = 0; ni < 4; ni++)
        acc[mi][ni] = __builtin_amdgcn_mfma_f32_16x16x32_bf16(af[mi], bfr[ni],
                                                              acc[mi][ni], 0, 0, 0);
    __syncthreads();
  }

  const int row0 = bm + wr * 64 + (l >> 4) * 4;
  const int region = bn >> 10;                    // 0 Q, 1 K, 2 V (uniform)
  if (region < 2) {
    const int base64 = (bn & 1023) + wc * 64;
    const int h = base64 >> 6;
    unsigned short* dst = region ? Kr : Qr;
    const float scale = region ? 1.0f : QSCALE;
    const size_t hb = (size_t)h * S_LEN * DKH;
#pragma unroll
    for (int mi = 0; mi < 4; mi++)
#pragma unroll
      for (int jj = 0; jj < 4; jj++) {
        const int s = row0 + mi * 16 + jj;
        const float2 cs0 = tab[s * 32 + lr];
        const float2 cs1 = tab[s * 32 + lr + 16];
        const float x1 = acc[mi][0][jj], x2 = acc[mi][2][jj];
        const float y1 = acc[mi][1][jj], y2 = acc[mi][3][jj];
        const float o0 = (x1 * cs0.x - x2 * cs0.y) * scale;
        const float o2 = (x2 * cs0.x + x1 * cs0.y) * scale;
        const float o1 = (y1 * cs1.x - y2 * cs1.y) * scale;
        const float o3 = (y2 * cs1.x + y1 * cs1.y) * scale;
        const size_t a = hb + (size_t)s * DKH + lr;
        dst[a]      = f2bf(o0);
        dst[a + 16] = f2bf(o1);
        dst[a + 32] = f2bf(o2);
        dst[a + 48] = f2bf(o3);
      }
  } else {
    // V: acc[mi][ni][0..3] are 4 consecutive s at fixed d -> short4 store
    const int colh = (bn - 2048) + wc * 64;       // multiple of 64
    const int h = colh >> 6;
    unsigned short* base = Vt + (size_t)h * DKH * S_LEN;
#pragma unroll
    for (int mi = 0; mi < 4; mi++) {
      const int s = row0 + mi * 16;
#pragma unroll
      for (int ni = 0; ni < 4; ni++) {
        const int d = ni * 16 + lr;
        ushort4v pk;
        pk[0] = f2bf(acc[mi][ni][0]);
        pk[1] = f2bf(acc[mi][ni][1]);
        pk[2] = f2bf(acc[mi][ni][2]);
        pk[3] = f2bf(acc[mi][ni][3]);
        *(ushort4v*)(base + (size_t)d * S_LEN + s) = pk;
      }
    }
  }
}

// ---------------------------------------------------------------------------
// m97-structure GEMM (f32 out): out = O . Wo^T.
// ---------------------------------------------------------------------------
__global__ __launch_bounds__(256) void gemm_lds_f32(const unsigned short* __restrict__ A,
                                                    const unsigned short* __restrict__ B,
                                                    float* __restrict__ Cp,
                                                    int M, int N, int K) {
  __shared__ __align__(16) unsigned short As[128 * 32];
  __shared__ __align__(16) unsigned short Bs[128 * 32];

  const int tid = threadIdx.x;
  const int l = tid & 63, w = tid >> 6;
  const int wr = w >> 1, wc = w & 1;
  const int bm = blockIdx.y * 128, bn = blockIdx.x * 128;
  const int lr = l & 15, lk = (l >> 4) * 8;

  f32x4 acc[4][4] = {};

  const unsigned short* Ag0 = A + (size_t)(bm + (tid >> 2)) * K + (tid & 3) * 8;
  const unsigned short* Ag1 = A + (size_t)(bm + 64 + (tid >> 2)) * K + (tid & 3) * 8;
  const unsigned short* Bg0 = B + (size_t)(bn + (tid >> 2)) * K + (tid & 3) * 8;
  const unsigned short* Bg1 = B + (size_t)(bn + 64 + (tid >> 2)) * K + (tid & 3) * 8;
  unsigned short* Ad0 = As + tid * 8;
  unsigned short* Ad1 = As + (tid + 256) * 8;
  unsigned short* Bd0 = Bs + tid * 8;
  unsigned short* Bd1 = Bs + (tid + 256) * 8;

  const unsigned short* Afr = As + (wr * 64 + lr) * 32 + lk;
  const unsigned short* Bfr = Bs + (wc * 64 + lr) * 32 + lk;

  for (int k0 = 0; k0 < K; k0 += 32) {
    GLDS16(Ag0 + k0, Ad0);
    GLDS16(Ag1 + k0, Ad1);
    GLDS16(Bg0 + k0, Bd0);
    GLDS16(Bg1 + k0, Bd1);
    __syncthreads();

    short8 af[4], bfr[4];
#pragma unroll
    for (int mi = 0; mi < 4; mi++) af[mi]  = *(const short8*)(Afr + mi * 16 * 32);
#pragma unroll
    for (int ni = 0; ni < 4; ni++) bfr[ni] = *(const short8*)(Bfr + ni * 16 * 32);

#pragma unroll
    for (int mi = 0; mi < 4; mi++)
#pragma unroll
      for (int ni = 0; ni < 4; ni++)
        acc[mi][ni] = __builtin_amdgcn_mfma_f32_16x16x32_bf16(af[mi], bfr[ni],
                                                              acc[mi][ni], 0, 0, 0);
    __syncthreads();
  }

  const int row0 = bm + wr * 64 + (l >> 4) * 4;
  const int col0 = bn + wc * 64 + lr;
#pragma unroll
  for (int mi = 0; mi < 4; mi++)
#pragma unroll
    for (int ni = 0; ni < 4; ni++)
#pragma unroll
      for (int j = 0; j < 4; j++)
        Cp[(size_t)(row0 + mi * 16 + j) * N + (col0 + ni * 16)] = acc[mi][ni][j];
}

// ---------------------------------------------------------------------------
// Flash attention: round-12 verified configuration. 2 adjacent q-subtiles
// (64 q-rows) per block, 64-key double-buffered windows, one barrier per
// window. Wave w: q-subtile w>>1, chunk parity w&1. Monotone longest-first
// qtile order (LPT-greedy under dynamic dispatch).
// ---------------------------------------------------------------------------
__global__ __launch_bounds__(256) void flash_attn_kernel(const unsigned short* __restrict__ Qr,
                                                         const unsigned short* __restrict__ Kr,
                                                         const unsigned short* __restrict__ Vt,
                                                         unsigned short* __restrict__ O) {
  // per buffer: [0,8K) K (64 keys x 128B), [8K,16K) V (64 d x 128B)
  __shared__ __align__(16) char smem[2][16384];

  const int tid = threadIdx.x;
  const int l  = tid & 63;
  const int w  = tid >> 6;            // wave 0..3
  const int r  = l & 31;
  const int hi = l >> 5;
  const int wsub = w >> 1;            // q-subtile 0/1
  const int wpar = w & 1;             // chunk parity

  // XCD-pinned head mapping + monotone longest-first q-pair order (r12).
  const int bx  = blockIdx.x;            // 0..1023
  const int xcd = bx & 7;
  const int j   = bx >> 3;               // 0..127
  const int h   = xcd * 2 + (j & 1);     // 2 heads per XCD
  const int jj  = 63 - (j >> 1);         // q-pair index, longest first
  const int q0  = jj * 64;

  const unsigned short* Qh = Qr + (size_t)h * S_LEN * DKH;
  const unsigned short* Kh = Kr + (size_t)h * S_LEN * DKH;
  const unsigned short* Vh = Vt + (size_t)h * DKH * S_LEN;

  const int qtile_w = 2 * jj + wsub;     // this wave's chunk-index ceiling
  const int qbase   = q0 + wsub * 32;

  // --- staging constants: K rows = keys (64 x 128B), V rows = d (64 x 128B)
  const int srow = tid >> 3;                                     // 0..31
  const int scol = (((tid & 7) * 16) ^ ((srow & 7) << 4)) >> 1;  // elem in row
  const size_t kbase = (size_t)srow * DKH + scol;    // Kh[key][d]
  const size_t vbase = (size_t)srow * S_LEN + scol;  // Vh[d][key]

  // --- fragment-read constants ---
  const int sw      = (r & 7) << 4;                // XOR swizzle for reads
  const int kfbyte  = (wpar * 32 + r) * 128;       // K row base (bytes)
  const int vfbyte0 = r * 128;                     // V rows r / r+32 (bytes)
  const int vfbyte1 = (r + 32) * 128;
  const int vcol    = wpar * 64 + hi * 16;         // V key-col base (bytes)

  // Q B-fragments for this wave's q-subtile
  short8 qf[4];
  {
    const unsigned short* qb = Qh + (size_t)(qbase + r) * 64 + hi * 8;
#pragma unroll
    for (int dc = 0; dc < 4; dc++) qf[dc] = *(const short8*)(qb + dc * 16);
  }

  f32x16 acc0 = {}, acc1 = {};     // O^T tiles: d 0..31 / 32..63, col=q
  float m = -1e30f, lsum = 0.0f;

  const int nwin = jj + 1;         // 64-key windows

  // --- prologue: stage window 0 into buf 0 ---
#pragma unroll
  for (int i = 0; i < 2; i++) {
    GLDS16(Kh + kbase + (size_t)i * 32 * DKH,   smem[0] + i * 4096 + tid * 16);
    GLDS16(Vh + vbase + (size_t)i * 32 * S_LEN, smem[0] + 8192 + i * 4096 + tid * 16);
  }
  __syncthreads();

  int buf = 0;
  for (int it = 0; it < nwin; it++) {
    // issue next window's staging into the other buffer (lands under compute)
    if (it + 1 < nwin) {
      char* sd = smem[buf ^ 1];
      const unsigned short* Kg = Kh + (size_t)(it + 1) * 64 * DKH;
      const unsigned short* Vg = Vh + (size_t)(it + 1) * 64;
#pragma unroll
      for (int i = 0; i < 2; i++) {
        GLDS16(Kg + kbase + (size_t)i * 32 * DKH,   sd + i * 4096 + tid * 16);
        GLDS16(Vg + vbase + (size_t)i * 32 * S_LEN, sd + 8192 + i * 4096 + tid * 16);
      }
    }

    const char* sm = smem[buf];
    const int c = 2 * it + wpar;
    if (c <= qtile_w) {
      // --- fragments from LDS (swizzled reads) ---
      short8 kf[4], vf[4];
#pragma unroll
      for (int dc = 0; dc < 4; dc++)
        kf[dc] = *(const short8*)(sm + kfbyte + ((dc * 32 + hi * 16) ^ sw));
#pragma unroll
      for (int kc = 0; kc < 2; kc++) {
        vf[kc]     = *(const short8*)(sm + 8192 + vfbyte0 + ((vcol + kc * 32) ^ sw));
        vf[2 + kc] = *(const short8*)(sm + 8192 + vfbyte1 + ((vcol + kc * 32) ^ sw));
      }

      // --- S^T = K . Q^T ---
      f32x16 st = {};
      __builtin_amdgcn_s_setprio(1);
      st = __builtin_amdgcn_mfma_f32_32x32x16_bf16(kf[0], qf[0], st, 0, 0, 0);
      st = __builtin_amdgcn_mfma_f32_32x32x16_bf16(kf[1], qf[1], st, 0, 0, 0);
      st = __builtin_amdgcn_mfma_f32_32x32x16_bf16(kf[2], qf[2], st, 0, 0, 0);
      st = __builtin_amdgcn_mfma_f32_32x32x16_bf16(kf[3], qf[3], st, 0, 0, 0);
      __builtin_amdgcn_s_setprio(0);

      // causal mask: only the diagonal chunk
      if (c == qtile_w) {
#pragma unroll
        for (int reg = 0; reg < 16; reg++) {
          const int koff = (reg & 3) + 8 * (reg >> 2) + 4 * hi;
          if (koff > r) st[reg] = -1e30f;
        }
      }

      // --- lane-local online softmax (exp2 domain) ---
      float t0 = fmaxf(fmaxf(st[0],  st[1]),  st[2]);
      float t1 = fmaxf(fmaxf(st[3],  st[4]),  st[5]);
      float t2 = fmaxf(fmaxf(st[6],  st[7]),  st[8]);
      float t3 = fmaxf(fmaxf(st[9],  st[10]), st[11]);
      float t4 = fmaxf(fmaxf(st[12], st[13]), st[14]);
      float pm = fmaxf(fmaxf(fmaxf(t0, t1), fmaxf(t2, t3)), fmaxf(t4, st[15]));
      pm = fmaxf(pm, __shfl_xor(pm, 32));

      if (!__all(pm <= m + 8.0f)) {     // defer-max (T13, THR=8)
        float mn  = fmaxf(m, pm);
        float scl = exp2f(m - mn);
        m = mn;
        lsum *= scl;
#pragma unroll
        for (int reg = 0; reg < 16; reg++) { acc0[reg] *= scl; acc1[reg] *= scl; }
      }

      float p2[16];
#pragma unroll
      for (int reg = 0; reg < 16; reg++) p2[reg] = exp2f(st[reg] - m);

      float s2[8];
#pragma unroll
      for (int i = 0; i < 8; i++) s2[i] = p2[2 * i] + p2[2 * i + 1];
#pragma unroll
      for (int i = 0; i < 4; i++) s2[i] = s2[i] + s2[i + 4];
      float rs = (s2[0] + s2[2]) + (s2[1] + s2[3]);
      rs += __shfl_xor(rs, 32);
      lsum += rs;

      // --- pack P to bf16 B-fragments (verified shfl_xor exchange) ---
      unsigned wd[8];
#pragma unroll
      for (int i = 0; i < 8; i++) {
        asm("v_cvt_pk_bf16_f32 %0, %1, %2" : "=v"(wd[i]) : "v"(p2[2 * i]), "v"(p2[2 * i + 1]));
      }
      unsigned pw[8];
#pragma unroll
      for (int i = 0; i < 8; i++) pw[i] = __shfl_xor(wd[i], 32);

      uint4v u0, u1;
      u0[0] = hi ? pw[2] : wd[0];
      u0[1] = hi ? pw[3] : wd[1];
      u0[2] = hi ? wd[2] : pw[0];
      u0[3] = hi ? wd[3] : pw[1];
      u1[0] = hi ? pw[6] : wd[4];
      u1[1] = hi ? pw[7] : wd[5];
      u1[2] = hi ? wd[6] : pw[4];
      u1[3] = hi ? wd[7] : pw[5];
      short8 pa0 = __builtin_bit_cast(short8, u0);
      short8 pa1 = __builtin_bit_cast(short8, u1);

      // --- O^T += V^T . P ---
      __builtin_amdgcn_s_setprio(1);
      acc0 = __builtin_amdgcn_mfma_f32_32x32x16_bf16(vf[0], pa0, acc0, 0, 0, 0);
      acc0 = __builtin_amdgcn_mfma_f32_32x32x16_bf16(vf[1], pa1, acc0, 0, 0, 0);
      acc1 = __builtin_amdgcn_mfma_f32_32x32x16_bf16(vf[2], pa0, acc1, 0, 0, 0);
      acc1 = __builtin_amdgcn_mfma_f32_32x32x16_bf16(vf[3], pa1, acc1, 0, 0, 0);
      __builtin_amdgcn_s_setprio(0);
    }

    __syncthreads();   // buf reads done + buf^1 staging complete
    buf ^= 1;
  }

  // --- LSE combine: 2 partials per q-subtile (buffers alias smem) ---
  unsigned (*oaccp)[32][33] = (unsigned (*)[32][33])smem;   // 16.9 KB
  float* mlm = (float*)((char*)smem + 16896);               // 128 floats
  float* mll = (float*)((char*)smem + 17408);               // 128 floats

  if (hi == 0) { mlm[w * 32 + r] = m; mll[w * 32 + r] = lsum; }
#pragma unroll
  for (int i = 0; i < 8; i++) {
    const int widx = 4 * (i >> 1) + 2 * hi + (i & 1);
    unsigned ua, ub;
    asm("v_cvt_pk_bf16_f32 %0, %1, %2" : "=v"(ua) : "v"(acc0[2 * i]), "v"(acc0[2 * i + 1]));
    asm("v_cvt_pk_bf16_f32 %0, %1, %2" : "=v"(ub) : "v"(acc1[2 * i]), "v"(acc1[2 * i + 1]));
    oaccp[w][r][widx]      = ua;
    oaccp[w][r][16 + widx] = ub;
  }
  __syncthreads();

  // thread -> (subtile st, q, word-group of 8)
  const int st  = tid >> 7;            // 0/1
  const int rem = tid & 127;
  const int q   = rem >> 2;            // 0..31
  const int c0  = (rem & 3) * 8;       // word index 0,8,16,24
  const int w0  = 2 * st, w1 = 2 * st + 1;

  const float m0 = mlm[w0 * 32 + q], m1 = mlm[w1 * 32 + q];
  const float mmax = fmaxf(m0, m1);
  const float sc0 = exp2f(m0 - mmax), sc1 = exp2f(m1 - mmax);
  const float ltot = sc0 * mll[w0 * 32 + q] + sc1 * mll[w1 * 32 + q];
  const float rinv = 1.0f / ltot;

  float vs[16];
#pragma unroll
  for (int i = 0; i < 8; i++) {
    unsigned ua = oaccp[w0][q][c0 + i];
    unsigned ub = oaccp[w1][q][c0 + i];
    vs[2 * i]     = sc0 * __builtin_bit_cast(float, ua << 16)
                  + sc1 * __builtin_bit_cast(float, ub << 16);
    vs[2 * i + 1] = sc0 * __builtin_bit_cast(float, ua & 0xFFFF0000u)
                  + sc1 * __builtin_bit_cast(float, ub & 0xFFFF0000u);
  }
  short8 ov0, ov1;
#pragma unroll
  for (int i = 0; i < 8; i++) {
    ov0[i] = (short)f2bf(vs[i] * rinv);
    ov1[i] = (short)f2bf(vs[8 + i] * rinv);
  }
  unsigned short* op = O + (size_t)(q0 + st * 32 + q) * DMODEL + h * 64 + c0 * 2;
  *(short8*)(op)     = ov0;
  *(short8*)(op + 8) = ov1;
}

// ---------------------------------------------------------------------------
// launch
// ---------------------------------------------------------------------------
extern "C" void kernel_launch(void* const* d_in, const int* in_sizes, int n_in,
                              void* d_out, int out_size, void* d_ws, size_t ws_size,
                              hipStream_t stream) {
  (void)in_sizes; (void)n_in; (void)out_size; (void)ws_size;
  const float* x    = (const float*)d_in[0];   // [4096,1024]
  const float* Wqkv = (const float*)d_in[1];   // [3072,1024]
  const float* Wo   = (const float*)d_in[2];   // [1024,1024]
  float* out = (float*)d_out;                  // [4096,1024]

  char* ws = (char*)d_ws;
  const size_t MB = 1u << 20;
  unsigned short* x_bf    = (unsigned short*)(ws + 0 * MB);
  unsigned short* wqkv_bf = (unsigned short*)(ws + 8 * MB);
  unsigned short* wo_bf   = (unsigned short*)(ws + 14 * MB);
  float2*         tab     = (float2*)(ws + 24 * MB);           //  1 MB
  unsigned short* Qr      = (unsigned short*)(ws + 40 * MB);
  unsigned short* Kr      = (unsigned short*)(ws + 48 * MB);
  unsigned short* Vt      = (unsigned short*)(ws + 56 * MB);
  unsigned short* Obf     = (unsigned short*)(ws + 64 * MB);

  // cvt (2,097,152 float4s) + rope table (131,072 entries) in one launch
  cvt_bf16_all<<<(CVT_TOTAL + 131072 + 255) / 256, 256, 0, stream>>>(
      x, x_bf, Wqkv, wqkv_bf, Wo, wo_bf, tab);

  // qkv = x . Wqkv^T with fused RoPE epilogue; V written transposed to Vt
  gemm_qkv<<<dim3(3072 / 128, 4096 / 128), 256, 0, stream>>>(x_bf, wqkv_bf, tab,
                                                             Qr, Kr, Vt);

  flash_attn_kernel<<<1024, 256, 0, stream>>>(Qr, Kr, Vt, Obf);

  // out = O . Wo^T : M=4096, N=1024, K=1024
  gemm_lds_f32<<<dim3(1024 / 128, 4096 / 128), 256, 0, stream>>>(Obf, wo_bf, out,
                                                                 4096, 1024, 1024);
}